// Round 2
// baseline (286.800 us; speedup 1.0000x reference)
//
#include <hip/hip_runtime.h>
#include <hip/hip_bf16.h>

typedef __bf16 bf16x8 __attribute__((ext_vector_type(8)));
typedef _Float16 f16x8 __attribute__((ext_vector_type(8)));
typedef unsigned short u16x8 __attribute__((ext_vector_type(8)));
typedef float f32x4 __attribute__((ext_vector_type(4)));
using bf16 = __hip_bfloat16;

constexpr int Cdim = 512;   // channels
constexpr int Nsp  = 4096;  // d*h*w
constexpr int NB   = 2;     // batch
constexpr float SCALE = 0.04419417382415922f;  // 512^-0.5
constexpr int EPITCH = 132; // epilogue LDS pitch (elems)

// async 16B global->LDS (m97 pattern). LDS dest must be wave-uniform base + lane*16.
#define GL2LDS(gaddr, laddr)                                                              \
    __builtin_amdgcn_global_load_lds((const __attribute__((address_space(1))) void*)(gaddr), \
                                     (__attribute__((address_space(3))) void*)(laddr), 16, 0, 0)

// ---------------------------------------------------------------- weights fp32 -> bf16 + zero lsum, one launch
__global__ __launch_bounds__(256) void k_cvt_all(const float* __restrict__ wq, const float* __restrict__ wk,
                                                 const float* __restrict__ wv, const float* __restrict__ wo,
                                                 bf16* __restrict__ wqkb, bf16* __restrict__ wvb,
                                                 bf16* __restrict__ wob, float* __restrict__ lsum) {
    if (blockIdx.x >= 256) {  // zero 8192-float lsum
        #pragma unroll
        for (int j = 0; j < 8; ++j)
            ((float4*)lsum)[8 * threadIdx.x + j] = float4{0.f, 0.f, 0.f, 0.f};
        return;
    }
    int i = blockIdx.x * 256 + threadIdx.x;  // 65536 float4 groups per weight
    float4 q = ((const float4*)wq)[i];
    float4 k = ((const float4*)wk)[i];
    float4 v = ((const float4*)wv)[i];
    float4 o = ((const float4*)wo)[i];
    bf16* dq = wqkb + (size_t)i * 4;
    dq[0] = __float2bfloat16(q.x); dq[1] = __float2bfloat16(q.y);
    dq[2] = __float2bfloat16(q.z); dq[3] = __float2bfloat16(q.w);
    bf16* dk = wqkb + 262144 + (size_t)i * 4;
    dk[0] = __float2bfloat16(k.x); dk[1] = __float2bfloat16(k.y);
    dk[2] = __float2bfloat16(k.z); dk[3] = __float2bfloat16(k.w);
    bf16* dv = wvb + (size_t)i * 4;
    dv[0] = __float2bfloat16(v.x); dv[1] = __float2bfloat16(v.y);
    dv[2] = __float2bfloat16(v.z); dv[3] = __float2bfloat16(v.w);
    bf16* dw = wob + (size_t)i * 4;
    dw[0] = __float2bfloat16(o.x); dw[1] = __float2bfloat16(o.y);
    dw[2] = __float2bfloat16(o.z); dw[3] = __float2bfloat16(o.w);
}

// ---------------------------------------------------------------- groupnorm stats
__global__ __launch_bounds__(256) void k_gn_stats(const float* __restrict__ x, float* __restrict__ stats) {
    int bg = blockIdx.x;  // 0..63
    const float4* p = (const float4*)(x + (size_t)bg * (16 * 4096));
    float s = 0.f, s2 = 0.f;
    for (int i = threadIdx.x; i < 16384; i += 256) {
        float4 v = p[i];
        s  += v.x + v.y + v.z + v.w;
        s2 += v.x * v.x + v.y * v.y + v.z * v.z + v.w * v.w;
    }
    #pragma unroll
    for (int off = 32; off; off >>= 1) { s += __shfl_xor(s, off); s2 += __shfl_xor(s2, off); }
    __shared__ float rs[4], rs2[4];
    int w = threadIdx.x >> 6;
    if ((threadIdx.x & 63) == 0) { rs[w] = s; rs2[w] = s2; }
    __syncthreads();
    if (threadIdx.x == 0) {
        float S = rs[0] + rs[1] + rs[2] + rs[3];
        float S2 = rs2[0] + rs2[1] + rs2[2] + rs2[3];
        float mean = S * (1.f / 65536.f);
        float var  = S2 * (1.f / 65536.f) - mean * mean;
        stats[bg * 2]     = mean;
        stats[bg * 2 + 1] = rsqrtf(var + 1e-6f);
    }
}

// ---------------------------------------------------------------- groupnorm apply + transpose -> ht[b,n,c] bf16
__global__ __launch_bounds__(256) void k_gn_apply(const float* __restrict__ x, const float* __restrict__ stats,
                                                  const float* __restrict__ gamma, const float* __restrict__ beta,
                                                  bf16* __restrict__ ht) {
    int b = blockIdx.y;
    int n0 = blockIdx.x * 64;
    int tid = threadIdx.x;
    __shared__ float tile[64][65];
    int nn_l = tid & 63, cc0 = tid >> 6;
    int cc_w = tid & 63, nn0 = tid >> 6;
    for (int c0 = 0; c0 < Cdim; c0 += 64) {
        #pragma unroll
        for (int p = 0; p < 16; ++p) {
            int cc = p * 4 + cc0;
            tile[cc][nn_l] = x[(size_t)(b * Cdim + c0 + cc) * Nsp + n0 + nn_l];
        }
        __syncthreads();
        int c = c0 + cc_w, g = c >> 4;
        float mean = stats[(b * 32 + g) * 2];
        float rstd = stats[(b * 32 + g) * 2 + 1];
        float ga = gamma[c], be = beta[c];
        #pragma unroll
        for (int p = 0; p < 16; ++p) {
            int nn = p * 4 + nn0;
            float v = tile[cc_w][nn];
            ht[(size_t)(b * Nsp + n0 + nn) * Cdim + c] = __float2bfloat16((v - mean) * rstd * ga + be);
        }
        __syncthreads();
    }
}

// ---------------------------------------------------------------- MFMA dtype dispatch
template <int DT>
__device__ __forceinline__ f32x4 mma16(u16x8 a, u16x8 b, f32x4 c) {
    if constexpr (DT == 0)
        return __builtin_amdgcn_mfma_f32_16x16x32_bf16(__builtin_bit_cast(bf16x8, a),
                                                       __builtin_bit_cast(bf16x8, b), c, 0, 0, 0);
    else
        return __builtin_amdgcn_mfma_f32_16x16x32_f16(__builtin_bit_cast(f16x8, a),
                                                      __builtin_bit_cast(f16x8, b), c, 0, 0, 0);
}

// ---------------------------------------------------------------- NT GEMM (m97 structure) + XOR-swizzled LDS
// Kept for the small-M GEMMs (V-proj, O-proj). See k_gemm_nt8 below for the big ones.
template <int BM, int DT, int OUTT, int BIAS, int RESID, int SPLITK, int EXPSUM>
__global__ __launch_bounds__(256) void k_gemm_nt(
    const void* __restrict__ Av, long long As, int lda,
    const void* __restrict__ Bv, long long Bs, int ldb,
    const float* __restrict__ bias, const float* __restrict__ bias2,
    const float* __restrict__ resid, long long Rs,
    float* __restrict__ lsum,
    void* __restrict__ outv, long long Os,
    int N, int K) {
    constexpr int MT = BM / 32;       // m-tiles per wave
    constexpr int SME_STAGE = (BM + 128) * 64;
    constexpr int SME_EPI   = BM * EPITCH;
    constexpr int SME = SME_STAGE > SME_EPI ? SME_STAGE : SME_EPI;
    const int bm = blockIdx.x, bn = blockIdx.y, zz = blockIdx.z;
    const int bt  = (SPLITK > 1) ? (zz % NB) : zz;
    const int ksl = (SPLITK > 1) ? (zz / NB) : 0;
    const int Kc = K / SPLITK;
    const int kbeg = ksl * Kc;
    const unsigned short* Ab = (const unsigned short*)Av + (size_t)bt * As;
    const unsigned short* Bb = (const unsigned short*)Bv + (size_t)bt * Bs;
    const int tid = threadIdx.x, lane = tid & 63, w = tid >> 6;
    const int quad = lane >> 4, l16 = lane & 15;
    const int wm = w >> 1, wn = w & 1;
    __shared__ __align__(16) unsigned short smem[SME];
    unsigned short (*Asub)[64] = (unsigned short(*)[64])smem;
    unsigned short (*Bsub)[64] = (unsigned short(*)[64])(smem + BM * 64);
    f32x4 zero4 = {0.f, 0.f, 0.f, 0.f};
    f32x4 acc[MT][4];
    #pragma unroll
    for (int i = 0; i < MT; ++i)
        #pragma unroll
        for (int j = 0; j < 4; ++j) acc[i][j] = zero4;
    const int row0 = bm * BM, col0 = bn * 128;
    const size_t ldab = (size_t)lda * 2, ldbb = (size_t)ldb * 2;
    const int lsw = (l16 & 7) * 8;  // fragment-read swizzle (elems)
    for (int k0 = kbeg; k0 < kbeg + Kc; k0 += 64) {
        const char* Abase = (const char*)Ab + (size_t)k0 * 2;
        const char* Bbase = (const char*)Bb + (size_t)k0 * 2;
        #pragma unroll
        for (int p = 0; p < BM / 32; ++p) {
            int o = p * 4096 + tid * 16;         // byte offset into A LDS tile
            int r = o >> 7;                      // row (128 B per row)
            int cs = ((o >> 4) ^ r) & 7;         // swizzled source chunk
            GL2LDS(Abase + (size_t)(row0 + r) * ldab + cs * 16, (char*)smem + o);
        }
        #pragma unroll
        for (int p = 0; p < 4; ++p) {
            int o = p * 4096 + tid * 16;
            int r = o >> 7;
            int cs = ((o >> 4) ^ r) & 7;
            GL2LDS(Bbase + (size_t)(col0 + r) * ldbb + cs * 16, (char*)smem + BM * 128 + o);
        }
        __syncthreads();
        #pragma unroll
        for (int ks = 0; ks < 2; ++ks) {
            u16x8 af[MT], bfr[4];
            #pragma unroll
            for (int t = 0; t < MT; ++t)
                af[t] = *(const u16x8*)&Asub[wm * (BM / 2) + t * 16 + l16][(ks * 32 + quad * 8) ^ lsw];
            #pragma unroll
            for (int t = 0; t < 4; ++t)
                bfr[t] = *(const u16x8*)&Bsub[wn * 64 + t * 16 + l16][(ks * 32 + quad * 8) ^ lsw];
            #pragma unroll
            for (int tm = 0; tm < MT; ++tm)
                #pragma unroll
                for (int tn = 0; tn < 4; ++tn) acc[tm][tn] = mma16<DT>(af[tm], bfr[tn], acc[tm][tn]);
        }
        __syncthreads();
    }

    if constexpr (OUTT == 2) {
        // scalar fp32 epilogue (final projection: bias + residual + fp32 out)
        #pragma unroll
        for (int tm = 0; tm < MT; ++tm)
            #pragma unroll
            for (int tn = 0; tn < 4; ++tn)
                #pragma unroll
                for (int r = 0; r < 4; ++r) {
                    int row = row0 + wm * (BM / 2) + tm * 16 + quad * 4 + r;
                    int col = col0 + wn * 64 + tn * 16 + l16;
                    float v = acc[tm][tn][r];
                    if constexpr (BIAS == 1) v += bias[row];
                    else if constexpr (BIAS == 2) v += bias[col];
                    if constexpr (RESID) v += resid[(size_t)bt * Rs + (size_t)row * N + col];
                    ((float*)outv)[(size_t)zz * Os + (size_t)row * N + col] = v;
                }
    } else {
        // ---- LDS-transpose epilogue (2-byte outputs) ----
        #pragma unroll
        for (int tn = 0; tn < 4; ++tn) {
            int colL = wn * 64 + tn * 16 + l16;
            float bc = 0.f;
            if constexpr (BIAS == 2) bc = bias[col0 + colL];
            else if constexpr (BIAS == 3) {
                int col = col0 + colL;
                bc = (col < 512) ? bias[col] : bias2[col - 512];
            }
            #pragma unroll
            for (int tm = 0; tm < MT; ++tm)
                #pragma unroll
                for (int r = 0; r < 4; ++r) {
                    int rowL = wm * (BM / 2) + tm * 16 + quad * 4 + r;
                    float v = acc[tm][tn][r];
                    if constexpr (BIAS == 1) v += bias[row0 + rowL];
                    else if constexpr (BIAS == 2) v += bc;
                    else if constexpr (BIAS == 3) {
                        int col = col0 + colL;
                        v = (col < 512) ? (v + bc) * SCALE : v + bc;
                    }
                    if constexpr (EXPSUM) v = __expf(v);
                    unsigned short hv;
                    if constexpr (OUTT == 1) { _Float16 h = (_Float16)v; hv = __builtin_bit_cast(unsigned short, h); }
                    else { bf16 h = __float2bfloat16(v); hv = __builtin_bit_cast(unsigned short, h); }
                    smem[rowL * EPITCH + colL] = hv;
                }
        }
        __syncthreads();
        // read phase: chunk = tid&15 (8 cols), rows (tid>>4)*(BM/16) + i; 16B coalesced stores
        const int cch = (tid & 15) * 8;
        const int rg  = (tid >> 4) * (BM / 16);
        #pragma unroll
        for (int i = 0; i < BM / 16; ++i) {
            int rowL = rg + i;
            u16x8 hv = *(const u16x8*)&smem[rowL * EPITCH + cch];
            *(u16x8*)((unsigned short*)outv + (size_t)zz * Os + (size_t)(row0 + rowL) * N + col0 + cch) = hv;
            if constexpr (EXPSUM) {
                float ps = 0.f;
                #pragma unroll
                for (int e = 0; e < 8; ++e) {
                    bf16 h = __builtin_bit_cast(bf16, hv[e]);
                    ps += __bfloat162float(h);
                }
                #pragma unroll
                for (int m = 1; m < 16; m <<= 1) ps += __shfl_xor(ps, m);
                if ((lane & 15) == 0) atomicAdd(lsum + (size_t)bt * Nsp + row0 + rowL, ps);
            }
        }
    }
}

// ---------------------------------------------------------------- deep-pipelined NT GEMM: 256x128 tile, ring-3 LDS,
// counted vmcnt across raw barriers (T3/T4), setprio around MFMA (T5). 512 threads, 8 waves (4m x 2n, 64x64 each).
// LDS: 3 slots x (A[256][64] + B[128][64]) bf16 = 144 KB. While computing tile t (slot t%3) the 6 global_load_lds
// of tile t+2 (slot (t+2)%3) are issued; the tile boundary waits lgkmcnt(0) + vmcnt(6) (tile t+1 landed, t+2 still
// in flight) and crosses a raw s_barrier -> the VMEM queue is never drained in the main loop.
// 2-byte bf16 output only. BIAS: 0=none, 3=fused QK. EXPSUM: exp + row-sum atomics (as in k_gemm_nt).
template <int DT, int BIAS, int SPLITK, int EXPSUM>
__global__ __launch_bounds__(512, 2) void k_gemm_nt8(
    const void* __restrict__ Av, long long As, int lda,
    const void* __restrict__ Bv, long long Bs, int ldb,
    const float* __restrict__ bias, const float* __restrict__ bias2,
    float* __restrict__ lsum,
    void* __restrict__ outv, long long Os,
    int N, int K) {
    constexpr int BM = 256, BN = 128;
    constexpr int SLOT = (BM + BN) * 64;                 // 24576 ushort per slot (49152 B)
    __shared__ __align__(16) unsigned short smem[3 * SLOT];  // 147456 B
    const int bm = blockIdx.x, bn = blockIdx.y, zz = blockIdx.z;
    const int bt  = (SPLITK > 1) ? (zz % NB) : zz;
    const int ksl = (SPLITK > 1) ? (zz / NB) : 0;
    const int Kc = K / SPLITK;
    const int kbeg = ksl * Kc;
    const int nt = Kc / 64;
    const unsigned short* Ab = (const unsigned short*)Av + (size_t)bt * As;
    const unsigned short* Bb = (const unsigned short*)Bv + (size_t)bt * Bs;
    const int tid = threadIdx.x, lane = tid & 63, w = tid >> 6;
    const int quad = lane >> 4, l16 = lane & 15;
    const int wm = w >> 1, wn = w & 1;                   // 4 m-waves x 2 n-waves
    const int row0 = bm * BM, col0 = bn * BN;
    const size_t ldab = (size_t)lda * 2, ldbb = (size_t)ldb * 2;
    const int lsw = (l16 & 7) * 8;

    // stage K-tile kt into slot s (6 x 16B global_load_lds per thread; XOR-swizzled source chunks)
    auto stage = [&](int kt, int s) {
        const char* Abase = (const char*)Ab + (size_t)(kbeg + kt * 64) * 2;
        const char* Bbase = (const char*)Bb + (size_t)(kbeg + kt * 64) * 2;
        char* dstA = (char*)smem + (size_t)s * (SLOT * 2);
        char* dstB = dstA + BM * 128;                    // A region = 32768 B
        #pragma unroll
        for (int p = 0; p < 4; ++p) {
            int o = p * 8192 + tid * 16;                 // [0, 32768)
            int r = o >> 7;                              // 128 B per row
            int cs = ((o >> 4) ^ r) & 7;
            GL2LDS(Abase + (size_t)(row0 + r) * ldab + cs * 16, dstA + o);
        }
        #pragma unroll
        for (int p = 0; p < 2; ++p) {
            int o = p * 8192 + tid * 16;                 // [0, 16384)
            int r = o >> 7;
            int cs = ((o >> 4) ^ r) & 7;
            GL2LDS(Bbase + (size_t)(col0 + r) * ldbb + cs * 16, dstB + o);
        }
    };

    f32x4 zero4 = {0.f, 0.f, 0.f, 0.f};
    f32x4 acc[4][4];
    #pragma unroll
    for (int i = 0; i < 4; ++i)
        #pragma unroll
        for (int j = 0; j < 4; ++j) acc[i][j] = zero4;

    // prologue: tiles 0 and 1 in flight; wait for tile 0 only (vmcnt(6) = tile 1's 6 loads may remain)
    stage(0, 0);
    asm volatile("" ::: "memory");  // keep tile-0/tile-1 issue order (vmcnt is FIFO)
    if (nt > 1) {
        stage(1, 1);
        asm volatile("s_waitcnt vmcnt(6)" ::: "memory");
    } else {
        asm volatile("s_waitcnt vmcnt(0)" ::: "memory");
    }
    __builtin_amdgcn_s_barrier();
    __builtin_amdgcn_sched_barrier(0);

    int sC = 0;  // slot of the tile being computed
    for (int t = 0; t < nt; ++t) {
        if (t + 2 < nt) {
            int sS = sC + 2; if (sS >= 3) sS -= 3;       // slot freed at the last boundary
            stage(t + 2, sS);
        }
        const unsigned short (*Asub)[64] = (const unsigned short(*)[64])(smem + sC * SLOT);
        const unsigned short (*Bsub)[64] = (const unsigned short(*)[64])(smem + sC * SLOT + BM * 64);
        #pragma unroll
        for (int ks = 0; ks < 2; ++ks) {
            u16x8 af[4], bfr[4];
            #pragma unroll
            for (int tm = 0; tm < 4; ++tm)
                af[tm] = *(const u16x8*)&Asub[wm * 64 + tm * 16 + l16][(ks * 32 + quad * 8) ^ lsw];
            #pragma unroll
            for (int tn = 0; tn < 4; ++tn)
                bfr[tn] = *(const u16x8*)&Bsub[wn * 64 + tn * 16 + l16][(ks * 32 + quad * 8) ^ lsw];
            __builtin_amdgcn_s_setprio(1);
            #pragma unroll
            for (int tm = 0; tm < 4; ++tm)
                #pragma unroll
                for (int tn = 0; tn < 4; ++tn) acc[tm][tn] = mma16<DT>(af[tm], bfr[tn], acc[tm][tn]);
            __builtin_amdgcn_s_setprio(0);
        }
        if (t + 1 < nt) {
            // drain own LDS reads (so no wave crosses the barrier with pending ds_reads of slot sC),
            // then wait for tile t+1's loads only — tile t+2's 6 stay in flight across the barrier.
            asm volatile("s_waitcnt lgkmcnt(0)" ::: "memory");
            if (t + 2 < nt) asm volatile("s_waitcnt vmcnt(6)" ::: "memory");
            else            asm volatile("s_waitcnt vmcnt(0)" ::: "memory");
            __builtin_amdgcn_s_barrier();
            __builtin_amdgcn_sched_barrier(0);
            sC = sC + 1; if (sC >= 3) sC -= 3;
        }
    }

    __syncthreads();  // full drain before reusing LDS for the transpose epilogue

    // ---- LDS-transpose epilogue (bf16 out), ported 1:1 from k_gemm_nt with the new wave geometry ----
    #pragma unroll
    for (int tn = 0; tn < 4; ++tn) {
        int colL = wn * 64 + tn * 16 + l16;              // 0..127
        float bc = 0.f;
        if constexpr (BIAS == 2) bc = bias[col0 + colL];
        else if constexpr (BIAS == 3) {
            int col = col0 + colL;
            bc = (col < 512) ? bias[col] : bias2[col - 512];
        }
        #pragma unroll
        for (int tm = 0; tm < 4; ++tm)
            #pragma unroll
            for (int r = 0; r < 4; ++r) {
                int rowL = wm * 64 + tm * 16 + quad * 4 + r;  // 0..255
                float v = acc[tm][tn][r];
                if constexpr (BIAS == 1) v += bias[row0 + rowL];
                else if constexpr (BIAS == 2) v += bc;
                else if constexpr (BIAS == 3) {
                    int col = col0 + colL;
                    v = (col < 512) ? (v + bc) * SCALE : v + bc;
                }
                if constexpr (EXPSUM) v = __expf(v);
                bf16 h = __float2bfloat16(v);
                smem[rowL * EPITCH + colL] = __builtin_bit_cast(unsigned short, h);
            }
    }
    __syncthreads();
    // read phase: 512 threads, 256 rows x 128 cols; chunk = tid&15, rows (tid>>4)*8 + i
    const int cch = (tid & 15) * 8;
    const int rg  = (tid >> 4) * 8;
    #pragma unroll
    for (int i = 0; i < 8; ++i) {
        int rowL = rg + i;
        u16x8 hv = *(const u16x8*)&smem[rowL * EPITCH + cch];
        *(u16x8*)((unsigned short*)outv + (size_t)zz * Os + (size_t)(row0 + rowL) * N + col0 + cch) = hv;
        if constexpr (EXPSUM) {
            float ps = 0.f;
            #pragma unroll
            for (int e = 0; e < 8; ++e) ps += __bfloat162float(__builtin_bit_cast(bf16, hv[e]));
            #pragma unroll
            for (int m = 1; m < 16; m <<= 1) ps += __shfl_xor(ps, m);
            if ((lane & 15) == 0) atomicAdd(lsum + (size_t)bt * Nsp + row0 + rowL, ps);
        }
    }
}

// ---------------------------------------------------------------- sum 4 bf16 split-K partials, /l -> bf16
__global__ __launch_bounds__(256) void k_reduce4(const bf16* __restrict__ P, const float* __restrict__ lsum,
                                                 bf16* __restrict__ O) {
    constexpr size_t SL = (size_t)NB * Nsp * Cdim;  // 4194304 elems per split slab
    size_t i = ((size_t)blockIdx.x * 256 + threadIdx.x) * 8;
    float linv = 1.f / lsum[i >> 9];  // flat/512 = b*Nsp + row
    union { bf16 h[8]; uint4 u; } a, b, c, d, r;
    a.u = *(const uint4*)(P + i);
    b.u = *(const uint4*)(P + SL + i);
    c.u = *(const uint4*)(P + 2 * SL + i);
    d.u = *(const uint4*)(P + 3 * SL + i);
    #pragma unroll
    for (int e = 0; e < 8; ++e) {
        float s = __bfloat162float(a.h[e]) + __bfloat162float(b.h[e]) +
                  __bfloat162float(c.h[e]) + __bfloat162float(d.h[e]);
        r.h[e] = __float2bfloat16(s * linv);
    }
    *(uint4*)(O + i) = r.u;
}

// ---------------------------------------------------------------- launcher
extern "C" void kernel_launch(void* const* d_in, const int* in_sizes, int n_in,
                              void* d_out, int out_size, void* d_ws, size_t ws_size,
                              hipStream_t stream) {
    const float* x     = (const float*)d_in[0];
    const float* gamma = (const float*)d_in[1];
    const float* beta  = (const float*)d_in[2];
    const float* wq = (const float*)d_in[3];  const float* bq = (const float*)d_in[4];
    const float* wk = (const float*)d_in[5];  const float* bk = (const float*)d_in[6];
    const float* wv = (const float*)d_in[7];  const float* bv = (const float*)d_in[8];
    const float* wo = (const float*)d_in[9];  const float* bo = (const float*)d_in[10];
    float* out = (float*)d_out;

    // workspace layout (Opart aliases ht+QKt+pad, all dead by PV time)
    char* ws = (char*)d_ws;
    float* stats = (float*)ws;
    size_t off = 1024;
    float* lsum = (float*)(ws + off); off += (size_t)NB * Nsp * 4 + 1024;  // 32 KB row sums
    bf16* wqkb = (bf16*)(ws + off); off += (size_t)1024 * 512 * 2;        // 1 MB  [1024][512] Q then K
    bf16* wvb  = (bf16*)(ws + off); off += (size_t)512 * 512 * 2;         // 0.5 MB
    bf16* wob  = (bf16*)(ws + off); off += (size_t)512 * 512 * 2;         // 0.5 MB
    bf16* Vm   = (bf16*)(ws + off); off += (size_t)NB * Nsp * Cdim * 2;   // 8 MB  [b][c][j]
    bf16* Ot   = (bf16*)(ws + off); off += (size_t)NB * Nsp * Cdim * 2;   // 8 MB  [b][i][c]
    bf16* Sm   = (bf16*)(ws + off); off += (size_t)NB * Nsp * Nsp * 2;    // 64 MB [b][i][j] (S then P=exp)
    bf16* ht   = (bf16*)(ws + off); off += (size_t)NB * Nsp * Cdim * 2;   // 8 MB  [b][n][c]
    bf16* QKt  = (bf16*)(ws + off); off += (size_t)NB * Nsp * 1024 * 2;   // 16 MB [b][n][1024]
    off += (size_t)8 << 20;                                               // 8 MB pad for Opart
    bf16* Opart = (bf16*)ht;  // 32 MB: 4 slabs x [b][i][c], aliases ht+QKt+pad

    k_cvt_all<<<257, 256, 0, stream>>>(wq, wk, wv, wo, wqkb, wvb, wob, lsum);
    k_gn_stats<<<64, 256, 0, stream>>>(x, stats);
    k_gn_apply<<<dim3(64, 2), 256, 0, stream>>>(x, stats, gamma, beta, ht);

    const long long hs = (long long)Nsp * Cdim;    // 2097152
    const long long qs = (long long)Nsp * 1024;    // 4194304
    const long long ss = (long long)Nsp * Nsp;     // 16777216

    // fused Q+K proj: QKt[i][co'] = (sum_k ht[i][k] wqk[co'][k] + b) (*SCALE for Q half)  [deep-pipelined]
    k_gemm_nt8<0, 3, 1, 0><<<dim3(16, 8, 2), 512, 0, stream>>>(
        ht, hs, 512, wqkb, 0, 512, bq, bk, nullptr, QKt, qs, 1024, 512);
    // V: Vm[co][j] = sum_k wv[co][k] ht[j][k] + bv  (M=512 -> old template)
    k_gemm_nt<128, 0, 0, 1, 0, 1, 0><<<dim3(4, 32, 2), 256, 0, stream>>>(
        wvb, 0, 512, ht, hs, 512, bv, nullptr, nullptr, 0, nullptr, Vm, hs, 4096, 512);
    // S = Q K^T -> P = exp(S) bf16 + row sums (M=N=4096, K=512; logits pre-scaled)  [deep-pipelined]
    k_gemm_nt8<0, 0, 1, 1><<<dim3(16, 32, 2), 512, 0, stream>>>(
        QKt, qs, 1024, QKt + 512, qs, 1024, nullptr, nullptr, lsum, Sm, ss, 4096, 512);
    // O_unnorm = P V^T split-K=4: partials[ksl*2+bt][i][c]  (M=4096, N=512, K=4096)  [deep-pipelined]
    k_gemm_nt8<0, 0, 4, 0><<<dim3(16, 4, 8), 512, 0, stream>>>(
        Sm, ss, 4096, Vm, hs, 4096, nullptr, nullptr, nullptr, Opart, hs, 512, 4096);
    // reduce 4 partials, divide by row sums -> Ot bf16
    k_reduce4<<<4096, 256, 0, stream>>>(Opart, lsum, Ot);
    // out[co][i] = x[co][i] + bo[co] + sum_k wo[co][k] Ot[i][k]  (fp32 out + residual, M=512 -> old template)
    k_gemm_nt<128, 0, 2, 1, 1, 1, 0><<<dim3(4, 32, 2), 256, 0, stream>>>(
        wob, 0, 512, Ot, hs, 512, bo, nullptr, x, hs, nullptr, out, hs, 4096, 512);
}

// Round 3
// 272.712 us; speedup vs baseline: 1.0517x; 1.0517x over previous
//
#include <hip/hip_runtime.h>
#include <hip/hip_bf16.h>

typedef __bf16 bf16x8 __attribute__((ext_vector_type(8)));
typedef _Float16 f16x8 __attribute__((ext_vector_type(8)));
typedef unsigned short u16x8 __attribute__((ext_vector_type(8)));
typedef float f32x4 __attribute__((ext_vector_type(4)));
using bf16 = __hip_bfloat16;

constexpr int Cdim = 512;   // channels
constexpr int Nsp  = 4096;  // d*h*w
constexpr int NB   = 2;     // batch
constexpr float SCALE = 0.04419417382415922f;  // 512^-0.5
constexpr int EPITCH = 132; // epilogue LDS pitch (elems) for k_gemm_nt

// async 16B global->LDS (m97 pattern). LDS dest must be wave-uniform base + lane*16.
#define GL2LDS(gaddr, laddr)                                                              \
    __builtin_amdgcn_global_load_lds((const __attribute__((address_space(1))) void*)(gaddr), \
                                     (__attribute__((address_space(3))) void*)(laddr), 16, 0, 0)

// ---------------------------------------------------------------- weights fp32 -> bf16 + zero lsum, one launch
__global__ __launch_bounds__(256) void k_cvt_all(const float* __restrict__ wq, const float* __restrict__ wk,
                                                 const float* __restrict__ wv, const float* __restrict__ wo,
                                                 bf16* __restrict__ wqkb, bf16* __restrict__ wvb,
                                                 bf16* __restrict__ wob, float* __restrict__ lsum) {
    if (blockIdx.x >= 256) {  // zero 8192-float lsum
        #pragma unroll
        for (int j = 0; j < 8; ++j)
            ((float4*)lsum)[8 * threadIdx.x + j] = float4{0.f, 0.f, 0.f, 0.f};
        return;
    }
    int i = blockIdx.x * 256 + threadIdx.x;  // 65536 float4 groups per weight
    float4 q = ((const float4*)wq)[i];
    float4 k = ((const float4*)wk)[i];
    float4 v = ((const float4*)wv)[i];
    float4 o = ((const float4*)wo)[i];
    bf16* dq = wqkb + (size_t)i * 4;
    dq[0] = __float2bfloat16(q.x); dq[1] = __float2bfloat16(q.y);
    dq[2] = __float2bfloat16(q.z); dq[3] = __float2bfloat16(q.w);
    bf16* dk = wqkb + 262144 + (size_t)i * 4;
    dk[0] = __float2bfloat16(k.x); dk[1] = __float2bfloat16(k.y);
    dk[2] = __float2bfloat16(k.z); dk[3] = __float2bfloat16(k.w);
    bf16* dv = wvb + (size_t)i * 4;
    dv[0] = __float2bfloat16(v.x); dv[1] = __float2bfloat16(v.y);
    dv[2] = __float2bfloat16(v.z); dv[3] = __float2bfloat16(v.w);
    bf16* dw = wob + (size_t)i * 4;
    dw[0] = __float2bfloat16(o.x); dw[1] = __float2bfloat16(o.y);
    dw[2] = __float2bfloat16(o.z); dw[3] = __float2bfloat16(o.w);
}

// ---------------------------------------------------------------- groupnorm stats
__global__ __launch_bounds__(256) void k_gn_stats(const float* __restrict__ x, float* __restrict__ stats) {
    int bg = blockIdx.x;  // 0..63
    const float4* p = (const float4*)(x + (size_t)bg * (16 * 4096));
    float s = 0.f, s2 = 0.f;
    for (int i = threadIdx.x; i < 16384; i += 256) {
        float4 v = p[i];
        s  += v.x + v.y + v.z + v.w;
        s2 += v.x * v.x + v.y * v.y + v.z * v.z + v.w * v.w;
    }
    #pragma unroll
    for (int off = 32; off; off >>= 1) { s += __shfl_xor(s, off); s2 += __shfl_xor(s2, off); }
    __shared__ float rs[4], rs2[4];
    int w = threadIdx.x >> 6;
    if ((threadIdx.x & 63) == 0) { rs[w] = s; rs2[w] = s2; }
    __syncthreads();
    if (threadIdx.x == 0) {
        float S = rs[0] + rs[1] + rs[2] + rs[3];
        float S2 = rs2[0] + rs2[1] + rs2[2] + rs2[3];
        float mean = S * (1.f / 65536.f);
        float var  = S2 * (1.f / 65536.f) - mean * mean;
        stats[bg * 2]     = mean;
        stats[bg * 2 + 1] = rsqrtf(var + 1e-6f);
    }
}

// ---------------------------------------------------------------- groupnorm apply + transpose -> ht[b,n,c] bf16
__global__ __launch_bounds__(256) void k_gn_apply(const float* __restrict__ x, const float* __restrict__ stats,
                                                  const float* __restrict__ gamma, const float* __restrict__ beta,
                                                  bf16* __restrict__ ht) {
    int b = blockIdx.y;
    int n0 = blockIdx.x * 64;
    int tid = threadIdx.x;
    __shared__ float tile[64][65];
    int nn_l = tid & 63, cc0 = tid >> 6;
    int cc_w = tid & 63, nn0 = tid >> 6;
    for (int c0 = 0; c0 < Cdim; c0 += 64) {
        #pragma unroll
        for (int p = 0; p < 16; ++p) {
            int cc = p * 4 + cc0;
            tile[cc][nn_l] = x[(size_t)(b * Cdim + c0 + cc) * Nsp + n0 + nn_l];
        }
        __syncthreads();
        int c = c0 + cc_w, g = c >> 4;
        float mean = stats[(b * 32 + g) * 2];
        float rstd = stats[(b * 32 + g) * 2 + 1];
        float ga = gamma[c], be = beta[c];
        #pragma unroll
        for (int p = 0; p < 16; ++p) {
            int nn = p * 4 + nn0;
            float v = tile[cc_w][nn];
            ht[(size_t)(b * Nsp + n0 + nn) * Cdim + c] = __float2bfloat16((v - mean) * rstd * ga + be);
        }
        __syncthreads();
    }
}

// ---------------------------------------------------------------- MFMA dtype dispatch
template <int DT>
__device__ __forceinline__ f32x4 mma16(u16x8 a, u16x8 b, f32x4 c) {
    if constexpr (DT == 0)
        return __builtin_amdgcn_mfma_f32_16x16x32_bf16(__builtin_bit_cast(bf16x8, a),
                                                       __builtin_bit_cast(bf16x8, b), c, 0, 0, 0);
    else
        return __builtin_amdgcn_mfma_f32_16x16x32_f16(__builtin_bit_cast(f16x8, a),
                                                      __builtin_bit_cast(f16x8, b), c, 0, 0, 0);
}

// ---------------------------------------------------------------- NT GEMM (m97 structure) + XOR-swizzled LDS
// Used for QK-proj, V-proj, O-proj (proven round-0 config).
template <int BM, int DT, int OUTT, int BIAS, int RESID, int SPLITK, int EXPSUM>
__global__ __launch_bounds__(256) void k_gemm_nt(
    const void* __restrict__ Av, long long As, int lda,
    const void* __restrict__ Bv, long long Bs, int ldb,
    const float* __restrict__ bias, const float* __restrict__ bias2,
    const float* __restrict__ resid, long long Rs,
    float* __restrict__ lsum,
    void* __restrict__ outv, long long Os,
    int N, int K) {
    constexpr int MT = BM / 32;       // m-tiles per wave
    constexpr int SME_STAGE = (BM + 128) * 64;
    constexpr int SME_EPI   = BM * EPITCH;
    constexpr int SME = SME_STAGE > SME_EPI ? SME_STAGE : SME_EPI;
    const int bm = blockIdx.x, bn = blockIdx.y, zz = blockIdx.z;
    const int bt  = (SPLITK > 1) ? (zz % NB) : zz;
    const int ksl = (SPLITK > 1) ? (zz / NB) : 0;
    const int Kc = K / SPLITK;
    const int kbeg = ksl * Kc;
    const unsigned short* Ab = (const unsigned short*)Av + (size_t)bt * As;
    const unsigned short* Bb = (const unsigned short*)Bv + (size_t)bt * Bs;
    const int tid = threadIdx.x, lane = tid & 63, w = tid >> 6;
    const int quad = lane >> 4, l16 = lane & 15;
    const int wm = w >> 1, wn = w & 1;
    __shared__ __align__(16) unsigned short smem[SME];
    unsigned short (*Asub)[64] = (unsigned short(*)[64])smem;
    unsigned short (*Bsub)[64] = (unsigned short(*)[64])(smem + BM * 64);
    f32x4 zero4 = {0.f, 0.f, 0.f, 0.f};
    f32x4 acc[MT][4];
    #pragma unroll
    for (int i = 0; i < MT; ++i)
        #pragma unroll
        for (int j = 0; j < 4; ++j) acc[i][j] = zero4;
    const int row0 = bm * BM, col0 = bn * 128;
    const size_t ldab = (size_t)lda * 2, ldbb = (size_t)ldb * 2;
    const int lsw = (l16 & 7) * 8;  // fragment-read swizzle (elems)
    for (int k0 = kbeg; k0 < kbeg + Kc; k0 += 64) {
        const char* Abase = (const char*)Ab + (size_t)k0 * 2;
        const char* Bbase = (const char*)Bb + (size_t)k0 * 2;
        #pragma unroll
        for (int p = 0; p < BM / 32; ++p) {
            int o = p * 4096 + tid * 16;         // byte offset into A LDS tile
            int r = o >> 7;                      // row (128 B per row)
            int cs = ((o >> 4) ^ r) & 7;         // swizzled source chunk
            GL2LDS(Abase + (size_t)(row0 + r) * ldab + cs * 16, (char*)smem + o);
        }
        #pragma unroll
        for (int p = 0; p < 4; ++p) {
            int o = p * 4096 + tid * 16;
            int r = o >> 7;
            int cs = ((o >> 4) ^ r) & 7;
            GL2LDS(Bbase + (size_t)(col0 + r) * ldbb + cs * 16, (char*)smem + BM * 128 + o);
        }
        __syncthreads();
        #pragma unroll
        for (int ks = 0; ks < 2; ++ks) {
            u16x8 af[MT], bfr[4];
            #pragma unroll
            for (int t = 0; t < MT; ++t)
                af[t] = *(const u16x8*)&Asub[wm * (BM / 2) + t * 16 + l16][(ks * 32 + quad * 8) ^ lsw];
            #pragma unroll
            for (int t = 0; t < 4; ++t)
                bfr[t] = *(const u16x8*)&Bsub[wn * 64 + t * 16 + l16][(ks * 32 + quad * 8) ^ lsw];
            #pragma unroll
            for (int tm = 0; tm < MT; ++tm)
                #pragma unroll
                for (int tn = 0; tn < 4; ++tn) acc[tm][tn] = mma16<DT>(af[tm], bfr[tn], acc[tm][tn]);
        }
        __syncthreads();
    }

    if constexpr (OUTT == 2) {
        // scalar fp32 epilogue (final projection: bias + residual + fp32 out)
        #pragma unroll
        for (int tm = 0; tm < MT; ++tm)
            #pragma unroll
            for (int tn = 0; tn < 4; ++tn)
                #pragma unroll
                for (int r = 0; r < 4; ++r) {
                    int row = row0 + wm * (BM / 2) + tm * 16 + quad * 4 + r;
                    int col = col0 + wn * 64 + tn * 16 + l16;
                    float v = acc[tm][tn][r];
                    if constexpr (BIAS == 1) v += bias[row];
                    else if constexpr (BIAS == 2) v += bias[col];
                    if constexpr (RESID) v += resid[(size_t)bt * Rs + (size_t)row * N + col];
                    ((float*)outv)[(size_t)zz * Os + (size_t)row * N + col] = v;
                }
    } else {
        // ---- LDS-transpose epilogue (2-byte outputs) ----
        #pragma unroll
        for (int tn = 0; tn < 4; ++tn) {
            int colL = wn * 64 + tn * 16 + l16;
            float bc = 0.f;
            if constexpr (BIAS == 2) bc = bias[col0 + colL];
            else if constexpr (BIAS == 3) {
                int col = col0 + colL;
                bc = (col < 512) ? bias[col] : bias2[col - 512];
            }
            #pragma unroll
            for (int tm = 0; tm < MT; ++tm)
                #pragma unroll
                for (int r = 0; r < 4; ++r) {
                    int rowL = wm * (BM / 2) + tm * 16 + quad * 4 + r;
                    float v = acc[tm][tn][r];
                    if constexpr (BIAS == 1) v += bias[row0 + rowL];
                    else if constexpr (BIAS == 2) v += bc;
                    else if constexpr (BIAS == 3) {
                        int col = col0 + colL;
                        v = (col < 512) ? (v + bc) * SCALE : v + bc;
                    }
                    if constexpr (EXPSUM) v = __expf(v);
                    unsigned short hv;
                    if constexpr (OUTT == 1) { _Float16 h = (_Float16)v; hv = __builtin_bit_cast(unsigned short, h); }
                    else { bf16 h = __float2bfloat16(v); hv = __builtin_bit_cast(unsigned short, h); }
                    smem[rowL * EPITCH + colL] = hv;
                }
        }
        __syncthreads();
        // read phase: chunk = tid&15 (8 cols), rows (tid>>4)*(BM/16) + i; 16B coalesced stores
        const int cch = (tid & 15) * 8;
        const int rg  = (tid >> 4) * (BM / 16);
        #pragma unroll
        for (int i = 0; i < BM / 16; ++i) {
            int rowL = rg + i;
            u16x8 hv = *(const u16x8*)&smem[rowL * EPITCH + cch];
            *(u16x8*)((unsigned short*)outv + (size_t)zz * Os + (size_t)(row0 + rowL) * N + col0 + cch) = hv;
            if constexpr (EXPSUM) {
                float ps = 0.f;
                #pragma unroll
                for (int e = 0; e < 8; ++e) {
                    bf16 h = __builtin_bit_cast(bf16, hv[e]);
                    ps += __bfloat162float(h);
                }
                #pragma unroll
                for (int m = 1; m < 16; m <<= 1) ps += __shfl_xor(ps, m);
                if ((lane & 15) == 0) atomicAdd(lsum + (size_t)bt * Nsp + row0 + rowL, ps);
            }
        }
    }
}

// ---------------------------------------------------------------- 8-phase 256x256 NT GEMM (m201 template, plain HIP)
// BK=64, 8 waves (2M x 4N), 512 threads, double-buffered LDS (2 x 64KB), INTERLEAVED frag mapping:
//   wave (wm,wn): m-frag f -> rows 16*(2f+wm), n-frag g -> cols 16*(4g+wn)
// so quadrant q(mh,nh) (4 m-frags x 2 n-frags x 2 k-slices = 16 MFMA) reads exactly one A-half + one B-half
// for ALL waves. Per phase: {ds_read subtile || stage 1 half (2 GL2LDS)} -> barrier -> lgkmcnt(0)+sched_barrier
// -> setprio(1) -> 16 MFMA -> setprio(0) -> barrier.  Counted vmcnt(4) once per K-tile at ph3 (2 halves stay in
// flight across the boundary); vmcnt(0) only at tile nt-2 (drain). Stage stream per tile t:
//   ph0: Bhi(t+1)  ph1: Ahi(t+1)  ph2: Alo(t+2)  ph3: Blo(t+2)     (region-disjoint from concurrent reads)
template <int KT, int SPLITK, int EXPSUM>
__global__ __launch_bounds__(512, 2) void k_gemm8p(
    const void* __restrict__ Av, long long As, int lda,
    const void* __restrict__ Bv, long long Bs, int ldb,
    float* __restrict__ lsum,
    void* __restrict__ outv, long long Os, int N) {
    constexpr int BM = 256;
    constexpr int Kc = KT / SPLITK;
    constexpr int nt = Kc / 64;                 // K-tiles (>= 4, even)
    constexpr int EP = 264;                     // epilogue pitch (16B-aligned rows)
    constexpr int DB = 32768;                   // ushorts per dbuf (A 16384 + B 16384)
    __shared__ __align__(16) unsigned short smem[BM * EP];  // 135168 B >= 2*DB*2 = 131072 B
    const int bm = blockIdx.x, bn = blockIdx.y, zz = blockIdx.z;
    const int bt  = (SPLITK > 1) ? (zz % NB) : zz;
    const int ksl = (SPLITK > 1) ? (zz / NB) : 0;
    const int kbeg = ksl * Kc;
    const unsigned short* Ab = (const unsigned short*)Av + (size_t)bt * As;
    const unsigned short* Bb = (const unsigned short*)Bv + (size_t)bt * Bs;
    const int tid = threadIdx.x, lane = tid & 63, w = tid >> 6;
    const int quad = lane >> 4, l16 = lane & 15;
    const int wm = w >> 2, wn = w & 3;          // 2 m-waves x 4 n-waves
    const int row0 = bm * BM, col0 = bn * BM;
    const size_t ldab = (size_t)lda * 2, ldbb = (size_t)ldb * 2;
    const int lsw = (l16 & 7) * 8;

// stage one 16KB half (2 x GL2LDS per thread). dest rows r in [hi*128, hi*128+128), XOR-pre-swizzled source.
#define STAGE_A8(kt, hi, db_) { \
    const char* _s = (const char*)Ab + (size_t)(kbeg + (kt) * 64) * 2; \
    char* _b = (char*)smem + (db_) * (DB * 2); \
    int _o = (hi) * 16384 + tid * 16; int _r = _o >> 7; int _c = ((_o >> 4) ^ _r) & 7; \
    GL2LDS(_s + (size_t)(row0 + _r) * ldab + _c * 16, _b + _o); \
    _o += 8192; _r = _o >> 7; _c = ((_o >> 4) ^ _r) & 7; \
    GL2LDS(_s + (size_t)(row0 + _r) * ldab + _c * 16, _b + _o); }
#define STAGE_B8(kt, hi, db_) { \
    const char* _s = (const char*)Bb + (size_t)(kbeg + (kt) * 64) * 2; \
    char* _b = (char*)smem + (db_) * (DB * 2) + 32768; \
    int _o = (hi) * 16384 + tid * 16; int _r = _o >> 7; int _c = ((_o >> 4) ^ _r) & 7; \
    GL2LDS(_s + (size_t)(col0 + _r) * ldbb + _c * 16, _b + _o); \
    _o += 8192; _r = _o >> 7; _c = ((_o >> 4) ^ _r) & 7; \
    GL2LDS(_s + (size_t)(col0 + _r) * ldbb + _c * 16, _b + _o); }
#define PH_SYNC() \
    __builtin_amdgcn_s_barrier(); \
    asm volatile("s_waitcnt lgkmcnt(0)" ::: "memory"); \
    __builtin_amdgcn_sched_barrier(0); \
    __builtin_amdgcn_s_setprio(1);
#define PH_END() \
    __builtin_amdgcn_s_setprio(0); \
    __builtin_amdgcn_s_barrier();

    f32x4 zero4 = {0.f, 0.f, 0.f, 0.f};
    f32x4 acc[8][4];
    #pragma unroll
    for (int i = 0; i < 8; ++i)
        #pragma unroll
        for (int j = 0; j < 4; ++j) acc[i][j] = zero4;

    // prologue: h1..h6 = Alo0,Blo0,Bhi0,Ahi0,Alo1,Blo1 ; vmcnt(4) -> tile0 landed; barrier
    STAGE_A8(0, 0, 0); STAGE_B8(0, 0, 0); STAGE_B8(0, 1, 0); STAGE_A8(0, 1, 0);
    STAGE_A8(1, 0, 1); STAGE_B8(1, 0, 1);
    asm volatile("s_waitcnt vmcnt(4)" ::: "memory");
    __builtin_amdgcn_s_barrier();
    __builtin_amdgcn_sched_barrier(0);

    u16x8 af[4][2], bA[2][2], bB[2][2];
    for (int t = 0; t < nt; ++t) {
        const int db = t & 1, dnx = db ^ 1;
        const unsigned short (*Adb)[64] = (const unsigned short(*)[64])(smem + db * DB);
        const unsigned short (*Bdb)[64] = (const unsigned short(*)[64])(smem + db * DB + 16384);
        // ---- ph0: quadrant (mh=0,nh=0): read Alo + Blo; stage Bhi(t+1) ----
        #pragma unroll
        for (int fl = 0; fl < 4; ++fl)
            #pragma unroll
            for (int ks = 0; ks < 2; ++ks)
                af[fl][ks] = *(const u16x8*)&Adb[16 * (2 * fl + wm) + l16][(ks * 32 + quad * 8) ^ lsw];
        #pragma unroll
        for (int gl = 0; gl < 2; ++gl)
            #pragma unroll
            for (int ks = 0; ks < 2; ++ks)
                bA[gl][ks] = *(const u16x8*)&Bdb[16 * (4 * gl + wn) + l16][(ks * 32 + quad * 8) ^ lsw];
        if (t + 1 < nt) STAGE_B8(t + 1, 1, dnx);
        PH_SYNC();
        #pragma unroll
        for (int fl = 0; fl < 4; ++fl)
            #pragma unroll
            for (int gl = 0; gl < 2; ++gl)
                #pragma unroll
                for (int ks = 0; ks < 2; ++ks)
                    acc[fl][gl] = mma16<0>(af[fl][ks], bA[gl][ks], acc[fl][gl]);
        PH_END();
        // ---- ph1: (mh=0,nh=1): read Bhi; stage Ahi(t+1) ----
        #pragma unroll
        for (int gl = 0; gl < 2; ++gl)
            #pragma unroll
            for (int ks = 0; ks < 2; ++ks)
                bB[gl][ks] = *(const u16x8*)&Bdb[16 * (4 * gl + 8 + wn) + l16][(ks * 32 + quad * 8) ^ lsw];
        if (t + 1 < nt) STAGE_A8(t + 1, 1, dnx);
        PH_SYNC();
        #pragma unroll
        for (int fl = 0; fl < 4; ++fl)
            #pragma unroll
            for (int gl = 0; gl < 2; ++gl)
                #pragma unroll
                for (int ks = 0; ks < 2; ++ks)
                    acc[fl][gl + 2] = mma16<0>(af[fl][ks], bB[gl][ks], acc[fl][gl + 2]);
        PH_END();
        // ---- ph2: (mh=1,nh=0): read Ahi (overwrite af); stage Alo(t+2) into CURRENT db (disjoint) ----
        #pragma unroll
        for (int fl = 0; fl < 4; ++fl)
            #pragma unroll
            for (int ks = 0; ks < 2; ++ks)
                af[fl][ks] = *(const u16x8*)&Adb[16 * (2 * fl + 8 + wm) + l16][(ks * 32 + quad * 8) ^ lsw];
        if (t + 2 < nt) STAGE_A8(t + 2, 0, db);
        PH_SYNC();
        #pragma unroll
        for (int fl = 0; fl < 4; ++fl)
            #pragma unroll
            for (int gl = 0; gl < 2; ++gl)
                #pragma unroll
                for (int ks = 0; ks < 2; ++ks)
                    acc[fl + 4][gl] = mma16<0>(af[fl][ks], bA[gl][ks], acc[fl + 4][gl]);
        PH_END();
        // ---- ph3: (mh=1,nh=1): no reads; stage Blo(t+2); per-tile counted vmcnt ----
        if (t + 2 < nt) STAGE_B8(t + 2, 0, db);
        if (t < nt - 2)      { asm volatile("s_waitcnt vmcnt(4)" ::: "memory"); }
        else if (t == nt - 2){ asm volatile("s_waitcnt vmcnt(0)" ::: "memory"); }
        PH_SYNC();
        #pragma unroll
        for (int fl = 0; fl < 4; ++fl)
            #pragma unroll
            for (int gl = 0; gl < 2; ++gl)
                #pragma unroll
                for (int ks = 0; ks < 2; ++ks)
                    acc[fl + 4][gl + 2] = mma16<0>(af[fl][ks], bB[gl][ks], acc[fl + 4][gl + 2]);
        PH_END();
    }
#undef STAGE_A8
#undef STAGE_B8
#undef PH_SYNC
#undef PH_END

    __syncthreads();  // full drain before LDS reuse

    // ---- LDS-transpose epilogue: 256x256 bf16 (+exp/rowsum) ----
    #pragma unroll
    for (int f = 0; f < 8; ++f)
        #pragma unroll
        for (int g = 0; g < 4; ++g) {
            int rowB = 16 * (2 * (f & 3) + 8 * (f >> 2) + wm) + quad * 4;
            int colL = 16 * (4 * (g & 1) + 8 * (g >> 1) + wn) + l16;
            #pragma unroll
            for (int r = 0; r < 4; ++r) {
                float v = acc[f][g][r];
                if constexpr (EXPSUM) v = __expf(v);
                bf16 h = __float2bfloat16(v);
                smem[(rowB + r) * EP + colL] = __builtin_bit_cast(unsigned short, h);
            }
        }
    __syncthreads();
    // read phase: 512 threads; chunk = tid&31 (8 cols of 256), rows (tid>>5)*16 + i
    const int cch = (tid & 31) * 8;
    const int rg  = (tid >> 5) * 16;
    #pragma unroll
    for (int i = 0; i < 16; ++i) {
        int rowL = rg + i;
        u16x8 hv = *(const u16x8*)&smem[rowL * EP + cch];
        *(u16x8*)((unsigned short*)outv + (size_t)zz * Os + (size_t)(row0 + rowL) * N + col0 + cch) = hv;
        if constexpr (EXPSUM) {
            float ps = 0.f;
            #pragma unroll
            for (int e = 0; e < 8; ++e) ps += __bfloat162float(__builtin_bit_cast(bf16, hv[e]));
            #pragma unroll
            for (int m = 1; m < 32; m <<= 1) ps += __shfl_xor(ps, m);
            if ((lane & 31) == 0) atomicAdd(lsum + (size_t)bt * Nsp + row0 + rowL, ps);
        }
    }
}

// ---------------------------------------------------------------- sum 4 bf16 split-K partials, /l -> bf16
__global__ __launch_bounds__(256) void k_reduce4(const bf16* __restrict__ P, const float* __restrict__ lsum,
                                                 bf16* __restrict__ O) {
    constexpr size_t SL = (size_t)NB * Nsp * Cdim;  // 4194304 elems per split slab
    size_t i = ((size_t)blockIdx.x * 256 + threadIdx.x) * 8;
    float linv = 1.f / lsum[i >> 9];  // flat/512 = b*Nsp + row
    union { bf16 h[8]; uint4 u; } a, b, c, d, r;
    a.u = *(const uint4*)(P + i);
    b.u = *(const uint4*)(P + SL + i);
    c.u = *(const uint4*)(P + 2 * SL + i);
    d.u = *(const uint4*)(P + 3 * SL + i);
    #pragma unroll
    for (int e = 0; e < 8; ++e) {
        float s = __bfloat162float(a.h[e]) + __bfloat162float(b.h[e]) +
                  __bfloat162float(c.h[e]) + __bfloat162float(d.h[e]);
        r.h[e] = __float2bfloat16(s * linv);
    }
    *(uint4*)(O + i) = r.u;
}

// ---------------------------------------------------------------- launcher
extern "C" void kernel_launch(void* const* d_in, const int* in_sizes, int n_in,
                              void* d_out, int out_size, void* d_ws, size_t ws_size,
                              hipStream_t stream) {
    const float* x     = (const float*)d_in[0];
    const float* gamma = (const float*)d_in[1];
    const float* beta  = (const float*)d_in[2];
    const float* wq = (const float*)d_in[3];  const float* bq = (const float*)d_in[4];
    const float* wk = (const float*)d_in[5];  const float* bk = (const float*)d_in[6];
    const float* wv = (const float*)d_in[7];  const float* bv = (const float*)d_in[8];
    const float* wo = (const float*)d_in[9];  const float* bo = (const float*)d_in[10];
    float* out = (float*)d_out;

    // workspace layout (Opart aliases ht+QKt+pad, all dead by PV time)
    char* ws = (char*)d_ws;
    float* stats = (float*)ws;
    size_t off = 1024;
    float* lsum = (float*)(ws + off); off += (size_t)NB * Nsp * 4 + 1024;  // 32 KB row sums
    bf16* wqkb = (bf16*)(ws + off); off += (size_t)1024 * 512 * 2;        // 1 MB  [1024][512] Q then K
    bf16* wvb  = (bf16*)(ws + off); off += (size_t)512 * 512 * 2;         // 0.5 MB
    bf16* wob  = (bf16*)(ws + off); off += (size_t)512 * 512 * 2;         // 0.5 MB
    bf16* Vm   = (bf16*)(ws + off); off += (size_t)NB * Nsp * Cdim * 2;   // 8 MB  [b][c][j]
    bf16* Ot   = (bf16*)(ws + off); off += (size_t)NB * Nsp * Cdim * 2;   // 8 MB  [b][i][c]
    bf16* Sm   = (bf16*)(ws + off); off += (size_t)NB * Nsp * Nsp * 2;    // 64 MB [b][i][j] (S then P=exp)
    bf16* ht   = (bf16*)(ws + off); off += (size_t)NB * Nsp * Cdim * 2;   // 8 MB  [b][n][c]
    bf16* QKt  = (bf16*)(ws + off); off += (size_t)NB * Nsp * 1024 * 2;   // 16 MB [b][n][1024]
    off += (size_t)8 << 20;                                               // 8 MB pad for Opart
    bf16* Opart = (bf16*)ht;  // 32 MB: 4 slabs x [b][i][c], aliases ht+QKt+pad

    k_cvt_all<<<257, 256, 0, stream>>>(wq, wk, wv, wo, wqkb, wvb, wob, lsum);
    k_gn_stats<<<64, 256, 0, stream>>>(x, stats);
    k_gn_apply<<<dim3(64, 2), 256, 0, stream>>>(x, stats, gamma, beta, ht);

    const long long hs = (long long)Nsp * Cdim;    // 2097152
    const long long qs = (long long)Nsp * 1024;    // 4194304
    const long long ss = (long long)Nsp * Nsp;     // 16777216

    // fused Q+K proj: QKt[i][co'] = (sum_k ht[i][k] wqk[co'][k] + b) (*SCALE for Q half)
    k_gemm_nt<128, 0, 0, 3, 0, 1, 0><<<dim3(32, 8, 2), 256, 0, stream>>>(
        ht, hs, 512, wqkb, 0, 512, bq, bk, nullptr, 0, nullptr, QKt, qs, 1024, 512);
    // V: Vm[co][j] = sum_k wv[co][k] ht[j][k] + bv  (M=512, N=4096, bf16 out)
    k_gemm_nt<128, 0, 0, 1, 0, 1, 0><<<dim3(4, 32, 2), 256, 0, stream>>>(
        wvb, 0, 512, ht, hs, 512, bv, nullptr, nullptr, 0, nullptr, Vm, hs, 4096, 512);
    // S = Q K^T -> P = exp(S) bf16 + row sums (M=N=4096, K=512; logits pre-scaled)  [8-phase]
    k_gemm8p<512, 1, 1><<<dim3(16, 16, 2), 512, 0, stream>>>(
        QKt, qs, 1024, QKt + 512, qs, 1024, lsum, Sm, ss, 4096);
    // O_unnorm = P V^T split-K=4: partials[ksl*2+bt][i][c]  (M=4096, N=512, K=4096)  [8-phase]
    k_gemm8p<4096, 4, 0><<<dim3(16, 2, 8), 512, 0, stream>>>(
        Sm, ss, 4096, Vm, hs, 4096, nullptr, Opart, hs, 512);
    // reduce 4 partials, divide by row sums -> Ot bf16
    k_reduce4<<<4096, 256, 0, stream>>>(Opart, lsum, Ot);
    // out[co][i] = x[co][i] + bo[co] + sum_k wo[co][k] Ot[i][k]  (fp32 out + residual)
    k_gemm_nt<128, 0, 2, 1, 1, 1, 0><<<dim3(4, 32, 2), 256, 0, stream>>>(
        wob, 0, 512, Ot, hs, 512, bo, nullptr, x, hs, nullptr, out, hs, 4096, 512);
}

// Round 4
// 253.086 us; speedup vs baseline: 1.1332x; 1.0775x over previous
//
#include <hip/hip_runtime.h>
#include <hip/hip_bf16.h>

typedef __bf16 bf16x8 __attribute__((ext_vector_type(8)));
typedef _Float16 f16x8 __attribute__((ext_vector_type(8)));
typedef unsigned short u16x8 __attribute__((ext_vector_type(8)));
typedef float f32x4 __attribute__((ext_vector_type(4)));
using bf16 = __hip_bfloat16;

constexpr int Cdim = 512;   // channels
constexpr int Nsp  = 4096;  // d*h*w
constexpr int NB   = 2;     // batch
constexpr float SCALE = 0.04419417382415922f;  // 512^-0.5
constexpr int EPITCH = 132; // epilogue LDS pitch (elems) for k_gemm_nt

// async 16B global->LDS (m97 pattern). LDS dest must be wave-uniform base + lane*16.
#define GL2LDS(gaddr, laddr)                                                              \
    __builtin_amdgcn_global_load_lds((const __attribute__((address_space(1))) void*)(gaddr), \
                                     (__attribute__((address_space(3))) void*)(laddr), 16, 0, 0)

// stage one 8KB [64 rows][64 elems] bf16 subtile: 1 GL2LDS per thread (512 thd),
// linear LDS dest, XOR-pre-swizzled global source chunk (verified k_gemm_nt pattern).
#define STG1(dst, src, ld) { int _o = tid * 16, _r = _o >> 7, _c = ((_o >> 4) ^ _r) & 7;      \
    GL2LDS((const unsigned short*)(src) + (size_t)_r * (ld) + _c * 8,                          \
           (unsigned short*)(dst) + (_o >> 1)); }

// ---------------------------------------------------------------- weights fp32 -> bf16 + zero lsum, one launch
__global__ __launch_bounds__(256) void k_cvt_all(const float* __restrict__ wq, const float* __restrict__ wk,
                                                 const float* __restrict__ wv, const float* __restrict__ wo,
                                                 bf16* __restrict__ wqkb, bf16* __restrict__ wvb,
                                                 bf16* __restrict__ wob, float* __restrict__ lsum) {
    if (blockIdx.x >= 256) {  // zero 8192-float lsum
        #pragma unroll
        for (int j = 0; j < 8; ++j)
            ((float4*)lsum)[8 * threadIdx.x + j] = float4{0.f, 0.f, 0.f, 0.f};
        return;
    }
    int i = blockIdx.x * 256 + threadIdx.x;  // 65536 float4 groups per weight
    float4 q = ((const float4*)wq)[i];
    float4 k = ((const float4*)wk)[i];
    float4 v = ((const float4*)wv)[i];
    float4 o = ((const float4*)wo)[i];
    bf16* dq = wqkb + (size_t)i * 4;
    dq[0] = __float2bfloat16(q.x); dq[1] = __float2bfloat16(q.y);
    dq[2] = __float2bfloat16(q.z); dq[3] = __float2bfloat16(q.w);
    bf16* dk = wqkb + 262144 + (size_t)i * 4;
    dk[0] = __float2bfloat16(k.x); dk[1] = __float2bfloat16(k.y);
    dk[2] = __float2bfloat16(k.z); dk[3] = __float2bfloat16(k.w);
    bf16* dv = wvb + (size_t)i * 4;
    dv[0] = __float2bfloat16(v.x); dv[1] = __float2bfloat16(v.y);
    dv[2] = __float2bfloat16(v.z); dv[3] = __float2bfloat16(v.w);
    bf16* dw = wob + (size_t)i * 4;
    dw[0] = __float2bfloat16(o.x); dw[1] = __float2bfloat16(o.y);
    dw[2] = __float2bfloat16(o.z); dw[3] = __float2bfloat16(o.w);
}

// ---------------------------------------------------------------- groupnorm stats
__global__ __launch_bounds__(256) void k_gn_stats(const float* __restrict__ x, float* __restrict__ stats) {
    int bg = blockIdx.x;  // 0..63
    const float4* p = (const float4*)(x + (size_t)bg * (16 * 4096));
    float s = 0.f, s2 = 0.f;
    for (int i = threadIdx.x; i < 16384; i += 256) {
        float4 v = p[i];
        s  += v.x + v.y + v.z + v.w;
        s2 += v.x * v.x + v.y * v.y + v.z * v.z + v.w * v.w;
    }
    #pragma unroll
    for (int off = 32; off; off >>= 1) { s += __shfl_xor(s, off); s2 += __shfl_xor(s2, off); }
    __shared__ float rs[4], rs2[4];
    int w = threadIdx.x >> 6;
    if ((threadIdx.x & 63) == 0) { rs[w] = s; rs2[w] = s2; }
    __syncthreads();
    if (threadIdx.x == 0) {
        float S = rs[0] + rs[1] + rs[2] + rs[3];
        float S2 = rs2[0] + rs2[1] + rs2[2] + rs2[3];
        float mean = S * (1.f / 65536.f);
        float var  = S2 * (1.f / 65536.f) - mean * mean;
        stats[bg * 2]     = mean;
        stats[bg * 2 + 1] = rsqrtf(var + 1e-6f);
    }
}

// ---------------------------------------------------------------- groupnorm apply + transpose -> ht[b,n,c] bf16
__global__ __launch_bounds__(256) void k_gn_apply(const float* __restrict__ x, const float* __restrict__ stats,
                                                  const float* __restrict__ gamma, const float* __restrict__ beta,
                                                  bf16* __restrict__ ht) {
    int b = blockIdx.y;
    int n0 = blockIdx.x * 64;
    int tid = threadIdx.x;
    __shared__ float tile[64][65];
    int nn_l = tid & 63, cc0 = tid >> 6;
    int cc_w = tid & 63, nn0 = tid >> 6;
    for (int c0 = 0; c0 < Cdim; c0 += 64) {
        #pragma unroll
        for (int p = 0; p < 16; ++p) {
            int cc = p * 4 + cc0;
            tile[cc][nn_l] = x[(size_t)(b * Cdim + c0 + cc) * Nsp + n0 + nn_l];
        }
        __syncthreads();
        int c = c0 + cc_w, g = c >> 4;
        float mean = stats[(b * 32 + g) * 2];
        float rstd = stats[(b * 32 + g) * 2 + 1];
        float ga = gamma[c], be = beta[c];
        #pragma unroll
        for (int p = 0; p < 16; ++p) {
            int nn = p * 4 + nn0;
            float v = tile[cc_w][nn];
            ht[(size_t)(b * Nsp + n0 + nn) * Cdim + c] = __float2bfloat16((v - mean) * rstd * ga + be);
        }
        __syncthreads();
    }
}

// ---------------------------------------------------------------- MFMA dtype dispatch
template <int DT>
__device__ __forceinline__ f32x4 mma16(u16x8 a, u16x8 b, f32x4 c) {
    if constexpr (DT == 0)
        return __builtin_amdgcn_mfma_f32_16x16x32_bf16(__builtin_bit_cast(bf16x8, a),
                                                       __builtin_bit_cast(bf16x8, b), c, 0, 0, 0);
    else
        return __builtin_amdgcn_mfma_f32_16x16x32_f16(__builtin_bit_cast(f16x8, a),
                                                      __builtin_bit_cast(f16x8, b), c, 0, 0, 0);
}

// ---------------------------------------------------------------- NT GEMM (m97 structure) + XOR-swizzled LDS
// Used for QK-proj, V-proj, O-proj (proven round-0 config).
template <int BM, int DT, int OUTT, int BIAS, int RESID, int SPLITK, int EXPSUM>
__global__ __launch_bounds__(256) void k_gemm_nt(
    const void* __restrict__ Av, long long As, int lda,
    const void* __restrict__ Bv, long long Bs, int ldb,
    const float* __restrict__ bias, const float* __restrict__ bias2,
    const float* __restrict__ resid, long long Rs,
    float* __restrict__ lsum,
    void* __restrict__ outv, long long Os,
    int N, int K) {
    constexpr int MT = BM / 32;       // m-tiles per wave
    constexpr int SME_STAGE = (BM + 128) * 64;
    constexpr int SME_EPI   = BM * EPITCH;
    constexpr int SME = SME_STAGE > SME_EPI ? SME_STAGE : SME_EPI;
    const int bm = blockIdx.x, bn = blockIdx.y, zz = blockIdx.z;
    const int bt  = (SPLITK > 1) ? (zz % NB) : zz;
    const int ksl = (SPLITK > 1) ? (zz / NB) : 0;
    const int Kc = K / SPLITK;
    const int kbeg = ksl * Kc;
    const unsigned short* Ab = (const unsigned short*)Av + (size_t)bt * As;
    const unsigned short* Bb = (const unsigned short*)Bv + (size_t)bt * Bs;
    const int tid = threadIdx.x, lane = tid & 63, w = tid >> 6;
    const int quad = lane >> 4, l16 = lane & 15;
    const int wm = w >> 1, wn = w & 1;
    __shared__ __align__(16) unsigned short smem[SME];
    unsigned short (*Asub)[64] = (unsigned short(*)[64])smem;
    unsigned short (*Bsub)[64] = (unsigned short(*)[64])(smem + BM * 64);
    f32x4 zero4 = {0.f, 0.f, 0.f, 0.f};
    f32x4 acc[MT][4];
    #pragma unroll
    for (int i = 0; i < MT; ++i)
        #pragma unroll
        for (int j = 0; j < 4; ++j) acc[i][j] = zero4;
    const int row0 = bm * BM, col0 = bn * 128;
    const size_t ldab = (size_t)lda * 2, ldbb = (size_t)ldb * 2;
    const int lsw = (l16 & 7) * 8;  // fragment-read swizzle (elems)
    for (int k0 = kbeg; k0 < kbeg + Kc; k0 += 64) {
        const char* Abase = (const char*)Ab + (size_t)k0 * 2;
        const char* Bbase = (const char*)Bb + (size_t)k0 * 2;
        #pragma unroll
        for (int p = 0; p < BM / 32; ++p) {
            int o = p * 4096 + tid * 16;         // byte offset into A LDS tile
            int r = o >> 7;                      // row (128 B per row)
            int cs = ((o >> 4) ^ r) & 7;         // swizzled source chunk
            GL2LDS(Abase + (size_t)(row0 + r) * ldab + cs * 16, (char*)smem + o);
        }
        #pragma unroll
        for (int p = 0; p < 4; ++p) {
            int o = p * 4096 + tid * 16;
            int r = o >> 7;
            int cs = ((o >> 4) ^ r) & 7;
            GL2LDS(Bbase + (size_t)(col0 + r) * ldbb + cs * 16, (char*)smem + BM * 128 + o);
        }
        __syncthreads();
        #pragma unroll
        for (int ks = 0; ks < 2; ++ks) {
            u16x8 af[MT], bfr[4];
            #pragma unroll
            for (int t = 0; t < MT; ++t)
                af[t] = *(const u16x8*)&Asub[wm * (BM / 2) + t * 16 + l16][(ks * 32 + quad * 8) ^ lsw];
            #pragma unroll
            for (int t = 0; t < 4; ++t)
                bfr[t] = *(const u16x8*)&Bsub[wn * 64 + t * 16 + l16][(ks * 32 + quad * 8) ^ lsw];
            #pragma unroll
            for (int tm = 0; tm < MT; ++tm)
                #pragma unroll
                for (int tn = 0; tn < 4; ++tn) acc[tm][tn] = mma16<DT>(af[tm], bfr[tn], acc[tm][tn]);
        }
        __syncthreads();
    }

    if constexpr (OUTT == 2) {
        // scalar fp32 epilogue (final projection: bias + residual + fp32 out)
        #pragma unroll
        for (int tm = 0; tm < MT; ++tm)
            #pragma unroll
            for (int tn = 0; tn < 4; ++tn)
                #pragma unroll
                for (int r = 0; r < 4; ++r) {
                    int row = row0 + wm * (BM / 2) + tm * 16 + quad * 4 + r;
                    int col = col0 + wn * 64 + tn * 16 + l16;
                    float v = acc[tm][tn][r];
                    if constexpr (BIAS == 1) v += bias[row];
                    else if constexpr (BIAS == 2) v += bias[col];
                    if constexpr (RESID) v += resid[(size_t)bt * Rs + (size_t)row * N + col];
                    ((float*)outv)[(size_t)zz * Os + (size_t)row * N + col] = v;
                }
    } else {
        // ---- LDS-transpose epilogue (2-byte outputs) ----
        #pragma unroll
        for (int tn = 0; tn < 4; ++tn) {
            int colL = wn * 64 + tn * 16 + l16;
            float bc = 0.f;
            if constexpr (BIAS == 2) bc = bias[col0 + colL];
            else if constexpr (BIAS == 3) {
                int col = col0 + colL;
                bc = (col < 512) ? bias[col] : bias2[col - 512];
            }
            #pragma unroll
            for (int tm = 0; tm < MT; ++tm)
                #pragma unroll
                for (int r = 0; r < 4; ++r) {
                    int rowL = wm * (BM / 2) + tm * 16 + quad * 4 + r;
                    float v = acc[tm][tn][r];
                    if constexpr (BIAS == 1) v += bias[row0 + rowL];
                    else if constexpr (BIAS == 2) v += bc;
                    else if constexpr (BIAS == 3) {
                        int col = col0 + colL;
                        v = (col < 512) ? (v + bc) * SCALE : v + bc;
                    }
                    if constexpr (EXPSUM) v = __expf(v);
                    unsigned short hv;
                    if constexpr (OUTT == 1) { _Float16 h = (_Float16)v; hv = __builtin_bit_cast(unsigned short, h); }
                    else { bf16 h = __float2bfloat16(v); hv = __builtin_bit_cast(unsigned short, h); }
                    smem[rowL * EPITCH + colL] = hv;
                }
        }
        __syncthreads();
        // read phase: chunk = tid&15 (8 cols), rows (tid>>4)*(BM/16) + i; 16B coalesced stores
        const int cch = (tid & 15) * 8;
        const int rg  = (tid >> 4) * (BM / 16);
        #pragma unroll
        for (int i = 0; i < BM / 16; ++i) {
            int rowL = rg + i;
            u16x8 hv = *(const u16x8*)&smem[rowL * EPITCH + cch];
            *(u16x8*)((unsigned short*)outv + (size_t)zz * Os + (size_t)(row0 + rowL) * N + col0 + cch) = hv;
            if constexpr (EXPSUM) {
                float ps = 0.f;
                #pragma unroll
                for (int e = 0; e < 8; ++e) {
                    bf16 h = __builtin_bit_cast(bf16, hv[e]);
                    ps += __bfloat162float(h);
                }
                #pragma unroll
                for (int m = 1; m < 16; m <<= 1) ps += __shfl_xor(ps, m);
                if ((lane & 15) == 0) atomicAdd(lsum + (size_t)bt * Nsp + row0 + rowL, ps);
            }
        }
    }
}

// ---------------------------------------------------------------- fused attention (no-max online softmax)
// Per block: 64 q-rows (i0), one j-half (2048 j, 32 tiles of 64), one batch. 8 waves (2 wm x 4 wn), 512 thd.
// LDS: Q resident 8x[64][64] (64KB) | H0 4x[64][64] (32KB) | H1 (32KB) | P [64][64] (8KB) = 136KB.
// Per j-tile (5 phases):
//   phS0: read K-d0 frags (H0) | stage K-d1->H1 | bar,lgkm0 | 16 MFMA (Q lazy) | vmcnt0,bar
//   phS1: read K-d1 frags (H1) | stage V-c0->H0 | bar,lgkm0 | 16 MFMA | bar
//   phEXP: stage V-c1->H1 | exp + rowsum + P writes | lgkm0, vmcnt(4) | bar
//   phPV0: read V-c0 frags (H0) | bar,lgkm0 | P frags lazy + 16 MFMA | vmcnt0,bar
//   phPV1: read V-c1 frags (H1) | stage K-d0(t+1)->H0 | bar,lgkm0 | 16 MFMA | vmcnt0,bar
// Every stage lands >=1 MFMA cluster before its consumer; every buffer read is lgkm-drained one
// barrier before restaging. Output: bf16 partial O (unnormalized) per j-half + lsum atomics.
__global__ __launch_bounds__(512, 2) void k_attn(const bf16* __restrict__ QKt_, const bf16* __restrict__ Vm_,
                                                 float* __restrict__ lsum, bf16* __restrict__ Opart_) {
    constexpr int NT = 32;
    const int bx = blockIdx.x, js = blockIdx.y, bt = blockIdx.z;
    const int i0 = bx * 64;
    const int jbase = js * 2048;
    const unsigned short* Qb = (const unsigned short*)QKt_ + (size_t)bt * ((size_t)Nsp * 1024);
    const unsigned short* Vb = (const unsigned short*)Vm_ + (size_t)bt * ((size_t)Nsp * Cdim);  // [c][j] ld 4096
    const int tid = threadIdx.x, lane = tid & 63, w = tid >> 6;
    const int quad = lane >> 4, l16 = lane & 15;
    const int wm = w >> 2, wn = w & 3;   // 2 m-waves x 4 n-waves
    const int lsw = (l16 & 7) * 8;
    __shared__ __align__(16) unsigned short smem[69632];   // 139264 B
    unsigned short* Q_l = smem;           // 8 x 4096
    unsigned short* H0  = smem + 32768;   // 4 x 4096
    unsigned short* H1  = smem + 49152;   // 4 x 4096
    unsigned short* P_l = smem + 65536;   // 4096

#define FR(sub, row, kc) (*(const u16x8*)&(sub)[(row) * 64 + ((kc) ^ lsw)])
#define PH_TOP() \
    __builtin_amdgcn_s_barrier(); \
    asm volatile("s_waitcnt lgkmcnt(0)" ::: "memory"); \
    __builtin_amdgcn_sched_barrier(0); \
    __builtin_amdgcn_s_setprio(1);

    f32x4 zero4 = {0.f, 0.f, 0.f, 0.f};
    f32x4 acc[2][8];
    #pragma unroll
    for (int m = 0; m < 2; ++m)
        #pragma unroll
        for (int n = 0; n < 8; ++n) acc[m][n] = zero4;
    float rsum[2][4] = {{0.f, 0.f, 0.f, 0.f}, {0.f, 0.f, 0.f, 0.f}};
    u16x8 pa[2][2];
    u16x8 fb[8];

    // prologue: Q (8 subs) + K-d0(t=0) -> H0 (4 subs); full wait (once)
    #pragma unroll
    for (int s = 0; s < 8; ++s) STG1(Q_l + s * 4096, Qb + (size_t)i0 * 1024 + s * 64, 1024);
    #pragma unroll
    for (int s = 0; s < 4; ++s) STG1(H0 + s * 4096, Qb + (size_t)jbase * 1024 + 512 + s * 64, 1024);
    asm volatile("s_waitcnt vmcnt(0)" ::: "memory");
    __builtin_amdgcn_s_barrier();
    __builtin_amdgcn_sched_barrier(0);

    for (int t = 0; t < NT; ++t) {
        const int j0 = jbase + t * 64;
        f32x4 aS[2] = {zero4, zero4};
        // ---- phS0: K-d0 from H0; stage K-d1 -> H1 ----
        #pragma unroll
        for (int ks = 0; ks < 8; ++ks)
            fb[ks] = FR(H0 + (ks >> 1) * 4096, wn * 16 + l16, (ks & 1) * 32 + quad * 8);
        #pragma unroll
        for (int s = 0; s < 4; ++s)
            STG1(H1 + s * 4096, Qb + (size_t)j0 * 1024 + 512 + 256 + s * 64, 1024);
        PH_TOP();
        #pragma unroll
        for (int ks = 0; ks < 8; ++ks)
            #pragma unroll
            for (int m = 0; m < 2; ++m) {
                u16x8 aq = FR(Q_l + (ks >> 1) * 4096, wm * 32 + m * 16 + l16, (ks & 1) * 32 + quad * 8);
                aS[m] = mma16<0>(aq, fb[ks], aS[m]);
            }
        __builtin_amdgcn_s_setprio(0);
        asm volatile("s_waitcnt vmcnt(0)" ::: "memory");   // K-d1 landed
        __builtin_amdgcn_s_barrier();
        // ---- phS1: K-d1 from H1; stage V-c0 -> H0 ----
        #pragma unroll
        for (int ks = 0; ks < 8; ++ks)
            fb[ks] = FR(H1 + (ks >> 1) * 4096, wn * 16 + l16, (ks & 1) * 32 + quad * 8);
        #pragma unroll
        for (int s = 0; s < 4; ++s)
            STG1(H0 + s * 4096, Vb + (size_t)(s * 64) * 4096 + j0, 4096);
        PH_TOP();
        #pragma unroll
        for (int ks = 0; ks < 8; ++ks)
            #pragma unroll
            for (int m = 0; m < 2; ++m) {
                u16x8 aq = FR(Q_l + (4 + (ks >> 1)) * 4096, wm * 32 + m * 16 + l16, (ks & 1) * 32 + quad * 8);
                aS[m] = mma16<0>(aq, fb[ks], aS[m]);
            }
        __builtin_amdgcn_s_setprio(0);
        __builtin_amdgcn_s_barrier();
        // ---- phEXP: stage V-c1 -> H1; exp + rowsum + P writes ----
        #pragma unroll
        for (int s = 0; s < 4; ++s)
            STG1(H1 + s * 4096, Vb + (size_t)(256 + s * 64) * 4096 + j0, 4096);
        #pragma unroll
        for (int m = 0; m < 2; ++m)
            #pragma unroll
            for (int r = 0; r < 4; ++r) {
                float p = __expf(aS[m][r]);
                rsum[m][r] += p;
                int il = wm * 32 + m * 16 + quad * 4 + r;
                bf16 h = __float2bfloat16(p);
                P_l[il * 64 + ((wn * 16 + l16) ^ ((il & 7) * 8))] = __builtin_bit_cast(unsigned short, h);
            }
        asm volatile("s_waitcnt lgkmcnt(0)" ::: "memory");  // P writes retired
        asm volatile("s_waitcnt vmcnt(4)" ::: "memory");    // V-c0 landed (V-c1 in flight)
        __builtin_amdgcn_s_barrier();
        __builtin_amdgcn_sched_barrier(0);
        // ---- phPV0: V-c0 from H0; P frags lazy ----
        #pragma unroll
        for (int nn = 0; nn < 4; ++nn)
            #pragma unroll
            for (int ks = 0; ks < 2; ++ks)
                fb[nn * 2 + ks] = FR(H0 + wn * 4096, nn * 16 + l16, ks * 32 + quad * 8);
        PH_TOP();
        #pragma unroll
        for (int m = 0; m < 2; ++m)
            #pragma unroll
            for (int ks = 0; ks < 2; ++ks)
                pa[m][ks] = *(const u16x8*)&P_l[(wm * 32 + m * 16 + l16) * 64 + ((ks * 32 + quad * 8) ^ lsw)];
        #pragma unroll
        for (int m = 0; m < 2; ++m)
            #pragma unroll
            for (int nn = 0; nn < 4; ++nn)
                #pragma unroll
                for (int ks = 0; ks < 2; ++ks)
                    acc[m][nn] = mma16<0>(pa[m][ks], fb[nn * 2 + ks], acc[m][nn]);
        __builtin_amdgcn_s_setprio(0);
        asm volatile("s_waitcnt vmcnt(0)" ::: "memory");    // V-c1 landed
        __builtin_amdgcn_s_barrier();
        // ---- phPV1: V-c1 from H1; stage K-d0(t+1) -> H0 ----
        #pragma unroll
        for (int nn = 0; nn < 4; ++nn)
            #pragma unroll
            for (int ks = 0; ks < 2; ++ks)
                fb[nn * 2 + ks] = FR(H1 + wn * 4096, nn * 16 + l16, ks * 32 + quad * 8);
        if (t + 1 < NT) {
            #pragma unroll
            for (int s = 0; s < 4; ++s)
                STG1(H0 + s * 4096, Qb + (size_t)(j0 + 64) * 1024 + 512 + s * 64, 1024);
        }
        PH_TOP();
        #pragma unroll
        for (int m = 0; m < 2; ++m)
            #pragma unroll
            for (int nn = 0; nn < 4; ++nn)
                #pragma unroll
                for (int ks = 0; ks < 2; ++ks)
                    acc[m][4 + nn] = mma16<0>(pa[m][ks], fb[nn * 2 + ks], acc[m][4 + nn]);
        __builtin_amdgcn_s_setprio(0);
        asm volatile("s_waitcnt vmcnt(0)" ::: "memory");    // K-d0(t+1) landed
        __builtin_amdgcn_s_barrier();
        __builtin_amdgcn_sched_barrier(0);
    }
#undef FR
#undef PH_TOP

    // ---- lsum: per-lane partials -> quad-row sums -> global atomics (j-split blocks both add) ----
    #pragma unroll
    for (int m = 0; m < 2; ++m)
        #pragma unroll
        for (int r = 0; r < 4; ++r) {
            float v = rsum[m][r];
            v += __shfl_xor(v, 1); v += __shfl_xor(v, 2); v += __shfl_xor(v, 4); v += __shfl_xor(v, 8);
            if (l16 == 0)
                atomicAdd(lsum + (size_t)bt * Nsp + i0 + wm * 32 + m * 16 + quad * 4 + r, v);
        }
    __syncthreads();
    // ---- O epilogue: LDS transpose (pitch 520, row&7 XOR) -> 16B coalesced partial stores ----
    #pragma unroll
    for (int m = 0; m < 2; ++m)
        #pragma unroll
        for (int h = 0; h < 2; ++h)
            #pragma unroll
            for (int nn = 0; nn < 4; ++nn) {
                int colL = h * 256 + wn * 64 + nn * 16 + l16;
                int rowB = wm * 32 + m * 16 + quad * 4;
                #pragma unroll
                for (int r = 0; r < 4; ++r) {
                    int rw = rowB + r;
                    bf16 hv = __float2bfloat16(acc[m][h * 4 + nn][r]);
                    smem[rw * 520 + (colL ^ ((rw & 7) * 8))] = __builtin_bit_cast(unsigned short, hv);
                }
            }
    __syncthreads();
    const int orow = tid >> 3, ocb = tid & 7;
    unsigned short* od = (unsigned short*)Opart_ + (size_t)js * ((size_t)NB * Nsp * Cdim) +
                         ((size_t)bt * Nsp + i0 + orow) * Cdim;
    #pragma unroll
    for (int it = 0; it < 8; ++it) {
        int cc = ocb + it * 8;
        u16x8 hv = *(const u16x8*)&smem[orow * 520 + ((cc * 8) ^ ((orow & 7) * 8))];
        *(u16x8*)(od + cc * 8) = hv;
    }
}

// ---------------------------------------------------------------- sum 2 bf16 j-split partials, /l -> bf16
__global__ __launch_bounds__(256) void k_reduce2(const bf16* __restrict__ P, const float* __restrict__ lsum,
                                                 bf16* __restrict__ O) {
    constexpr size_t SL = (size_t)NB * Nsp * Cdim;  // 4194304 elems per slab
    size_t i = ((size_t)blockIdx.x * 256 + threadIdx.x) * 8;
    float linv = 1.f / lsum[i >> 9];  // flat/512 = b*Nsp + row
    union { bf16 h[8]; uint4 u; } a, b, r;
    a.u = *(const uint4*)(P + i);
    b.u = *(const uint4*)(P + SL + i);
    #pragma unroll
    for (int e = 0; e < 8; ++e) {
        float s = __bfloat162float(a.h[e]) + __bfloat162float(b.h[e]);
        r.h[e] = __float2bfloat16(s * linv);
    }
    *(uint4*)(O + i) = r.u;
}

// ---------------------------------------------------------------- launcher
extern "C" void kernel_launch(void* const* d_in, const int* in_sizes, int n_in,
                              void* d_out, int out_size, void* d_ws, size_t ws_size,
                              hipStream_t stream) {
    const float* x     = (const float*)d_in[0];
    const float* gamma = (const float*)d_in[1];
    const float* beta  = (const float*)d_in[2];
    const float* wq = (const float*)d_in[3];  const float* bq = (const float*)d_in[4];
    const float* wk = (const float*)d_in[5];  const float* bk = (const float*)d_in[6];
    const float* wv = (const float*)d_in[7];  const float* bv = (const float*)d_in[8];
    const float* wo = (const float*)d_in[9];  const float* bo = (const float*)d_in[10];
    float* out = (float*)d_out;

    // workspace layout
    char* ws = (char*)d_ws;
    float* stats = (float*)ws;
    size_t off = 1024;
    float* lsum = (float*)(ws + off); off += (size_t)NB * Nsp * 4 + 1024;  // 32 KB row sums
    bf16* wqkb = (bf16*)(ws + off); off += (size_t)1024 * 512 * 2;        // 1 MB  [1024][512] Q then K
    bf16* wvb  = (bf16*)(ws + off); off += (size_t)512 * 512 * 2;         // 0.5 MB
    bf16* wob  = (bf16*)(ws + off); off += (size_t)512 * 512 * 2;         // 0.5 MB
    bf16* Vm   = (bf16*)(ws + off); off += (size_t)NB * Nsp * Cdim * 2;   // 8 MB  [b][c][j]
    bf16* Ot   = (bf16*)(ws + off); off += (size_t)NB * Nsp * Cdim * 2;   // 8 MB  [b][i][c]
    bf16* Opart = (bf16*)(ws + off); off += (size_t)2 * NB * Nsp * Cdim * 2;  // 16 MB: 2 j-split slabs
    bf16* ht   = (bf16*)(ws + off); off += (size_t)NB * Nsp * Cdim * 2;   // 8 MB  [b][n][c]
    bf16* QKt  = (bf16*)(ws + off); off += (size_t)NB * Nsp * 1024 * 2;   // 16 MB [b][n][1024]

    k_cvt_all<<<257, 256, 0, stream>>>(wq, wk, wv, wo, wqkb, wvb, wob, lsum);
    k_gn_stats<<<64, 256, 0, stream>>>(x, stats);
    k_gn_apply<<<dim3(64, 2), 256, 0, stream>>>(x, stats, gamma, beta, ht);

    const long long hs = (long long)Nsp * Cdim;    // 2097152
    const long long qs = (long long)Nsp * 1024;    // 4194304

    // fused Q+K proj: QKt[i][co'] = (sum_k ht[i][k] wqk[co'][k] + b) (*SCALE for Q half)
    k_gemm_nt<128, 0, 0, 3, 0, 1, 0><<<dim3(32, 8, 2), 256, 0, stream>>>(
        ht, hs, 512, wqkb, 0, 512, bq, bk, nullptr, 0, nullptr, QKt, qs, 1024, 512);
    // V: Vm[co][j] = sum_k wv[co][k] ht[j][k] + bv  (M=512, N=4096, bf16 out)
    k_gemm_nt<128, 0, 0, 1, 0, 1, 0><<<dim3(4, 32, 2), 256, 0, stream>>>(
        wvb, 0, 512, ht, hs, 512, bv, nullptr, nullptr, 0, nullptr, Vm, hs, 4096, 512);
    // fused attention: O_partial (2 j-split slabs) + lsum
    k_attn<<<dim3(64, 2, 2), 512, 0, stream>>>(QKt, Vm, lsum, Opart);
    // combine j-split partials, divide by row sums -> Ot bf16
    k_reduce2<<<2048, 256, 0, stream>>>(Opart, lsum, Ot);
    // out[co][i] = x[co][i] + bo[co] + sum_k wo[co][k] Ot[i][k]  (fp32 out + residual)
    k_gemm_nt<128, 0, 2, 1, 1, 1, 0><<<dim3(4, 32, 2), 256, 0, stream>>>(
        wob, 0, 512, Ot, hs, 512, bo, nullptr, x, hs, nullptr, out, hs, 4096, 512);
}